// Round 1
// baseline (688.551 us; speedup 1.0000x reference)
//
#include <hip/hip_runtime.h>
#include <math.h>

#define HH 960
#define WW 1920
#define LTOT 32
#define HWSZ (HH * WW)
#define NRAYS 65536
#define SIG_OFF_F 5.0f
#define DMIN_F 2.0f

__device__ __forceinline__ float sigmoidf(float x) {
    return 1.0f / (1.0f + expf(-x));
}

// One thread per (ray, layer). 32 lanes (= half a wave) cooperate on one ray:
//  - each lane computes its layer's sphere intersection + alpha bilinear sample
//  - even lanes additionally fetch the 3-channel rgb bilinear sample (shared
//    with the odd sibling lane, matching gx[::NSUB] + repeat in the reference)
//  - transmittance = exclusive prefix product of (1 - alpha) via shfl_up scan
//  - output = shfl_xor reduction of weight * rgb over the 32 lanes
__global__ __launch_bounds__(256) void msi_forward(
    const float* __restrict__ origins,
    const float* __restrict__ directions,
    const float* __restrict__ alpha,
    const float* __restrict__ rgb,
    const float* __restrict__ layer_deltas,
    const float* __restrict__ center,
    float* __restrict__ out)
{
    __shared__ float s_radii[LTOT];
    if (threadIdx.x == 0) {
        // radii = cumsum([DMIN] ++ exp(layer_deltas)) — sequential f32 to match ref
        float r = DMIN_F;
        s_radii[0] = r;
        for (int i = 0; i < LTOT - 1; ++i) {
            r += expf(layer_deltas[i]);
            s_radii[i + 1] = r;
        }
    }
    __syncthreads();

    const int gid  = blockIdx.x * 256 + threadIdx.x;
    const int ray  = gid >> 5;
    const int lane = threadIdx.x & 31;   // layer index for this lane

    // Ray data (uniform across the 32-lane group; cache-broadcast)
    const float cx = center[0], cy = center[1], cz = center[2];
    const float ox = origins[ray * 3 + 0];
    const float oy = origins[ray * 3 + 1];
    const float oz = origins[ray * 3 + 2];
    const float dxv = directions[ray * 3 + 0];
    const float dyv = directions[ray * 3 + 1];
    const float dzv = directions[ray * 3 + 2];

    const float rx = ox - cx, ry = oy - cy, rz = oz - cz;
    const float a  = dxv * dxv + dyv * dyv + dzv * dzv;
    const float b  = 2.0f * (dxv * rx + dyv * ry + dzv * rz);
    const float c0 = rx * rx + ry * ry + rz * rz;

    // Sphere intersection for this lane's layer
    const float r    = s_radii[lane];
    const float c    = c0 - r * r;
    const float disc = b * b - 4.0f * a * c;
    const float sq   = sqrtf(fmaxf(disc, 0.0f));
    const float t0   = (-b + sq) / (2.0f * a);
    const float t1   = (-b - sq) / (2.0f * a);
    const bool  mask = (t0 * t1) < 0.0f;

    const float px = (ox + dxv * t0) - cx;
    const float py = (oy + dyv * t0) - cy;
    const float pz = (oz + dzv * t0) - cz;
    const float nx = px / r, ny = py / r, nz = pz / r;

    const float gx = nz;
    const float gy = atan2f(ny, -nx) * 0.31830988618379067f;  // / pi

    // Bilinear setup (clip semantics identical to reference)
    const float x   = (gx + 1.0f) * 0.5f * (float)(WW - 1);
    const float y   = (gy + 1.0f) * 0.5f * (float)(HH - 1);
    const float x0f = floorf(x), y0f = floorf(y);
    const float wx  = x - x0f,  wy  = y - y0f;
    int ix0 = (int)x0f, iy0 = (int)y0f;
    int ix1 = ix0 + 1,  iy1 = iy0 + 1;
    ix0 = min(max(ix0, 0), WW - 1);
    ix1 = min(max(ix1, 0), WW - 1);
    iy0 = min(max(iy0, 0), HH - 1);
    iy1 = min(max(iy1, 0), HH - 1);

    const float w00 = (1.0f - wx) * (1.0f - wy);
    const float w01 = wx * (1.0f - wy);
    const float w10 = (1.0f - wx) * wy;
    const float w11 = wx * wy;

    const int i00 = iy0 * WW + ix0;
    const int i01 = iy0 * WW + ix1;
    const int i10 = iy1 * WW + ix0;
    const int i11 = iy1 * WW + ix1;

    // Alpha sample for this layer
    const float* ap = alpha + (size_t)lane * HWSZ;
    const float sv = ap[i00] * w00 + ap[i01] * w01 + ap[i10] * w10 + ap[i11] * w11;
    float av = sigmoidf(sv - SIG_OFF_F);
    av = mask ? av : 0.0f;

    // RGB: sampled at even-layer coords (gx[::NSUB] + repeat). Even lanes fetch.
    float cr = 0.0f, cg = 0.0f, cb = 0.0f;
    if ((lane & 1) == 0) {
        const float* rp = rgb + (size_t)(lane >> 1) * 3 * HWSZ;
        {
            const float* q = rp;
            cr = sigmoidf(q[i00] * w00 + q[i01] * w01 + q[i10] * w10 + q[i11] * w11);
        }
        {
            const float* q = rp + HWSZ;
            cg = sigmoidf(q[i00] * w00 + q[i01] * w01 + q[i10] * w10 + q[i11] * w11);
        }
        {
            const float* q = rp + 2 * HWSZ;
            cb = sigmoidf(q[i00] * w00 + q[i01] * w01 + q[i10] * w10 + q[i11] * w11);
        }
    }
    const int src = lane & ~1;
    cr = __shfl(cr, src, 32);
    cg = __shfl(cg, src, 32);
    cb = __shfl(cb, src, 32);

    // Exclusive prefix product of (1 - alpha) over the 32-lane group
    float p = 1.0f - av;
    #pragma unroll
    for (int off = 1; off < 32; off <<= 1) {
        const float v = __shfl_up(p, off, 32);
        if (lane >= off) p *= v;
    }
    float trans = __shfl_up(p, 1, 32);
    if (lane == 0) trans = 1.0f;
    const float wgt = av * trans;

    // out[n][c] = sum_l weight * rgb
    float accR = wgt * cr;
    float accG = wgt * cg;
    float accB = wgt * cb;
    #pragma unroll
    for (int off = 16; off >= 1; off >>= 1) {
        accR += __shfl_xor(accR, off, 32);
        accG += __shfl_xor(accG, off, 32);
        accB += __shfl_xor(accB, off, 32);
    }
    if (lane == 0) {
        out[ray * 3 + 0] = accR;
        out[ray * 3 + 1] = accG;
        out[ray * 3 + 2] = accB;
    }
}

extern "C" void kernel_launch(void* const* d_in, const int* in_sizes, int n_in,
                              void* d_out, int out_size, void* d_ws, size_t ws_size,
                              hipStream_t stream) {
    const float* origins      = (const float*)d_in[0];
    const float* directions   = (const float*)d_in[1];
    const float* alpha        = (const float*)d_in[2];
    const float* rgb          = (const float*)d_in[3];
    const float* layer_deltas = (const float*)d_in[4];
    const float* center       = (const float*)d_in[5];
    float* out = (float*)d_out;

    const int total   = NRAYS * LTOT;          // one thread per (ray, layer)
    const int threads = 256;
    const int blocks  = total / threads;       // 8192
    msi_forward<<<blocks, threads, 0, stream>>>(origins, directions, alpha, rgb,
                                                layer_deltas, center, out);
}

// Round 2
// 654.782 us; speedup vs baseline: 1.0516x; 1.0516x over previous
//
#include <hip/hip_runtime.h>
#include <math.h>

#define HH 960
#define WW 1920
#define LTOT 32
#define HWSZ (HH * WW)
#define NRAYS 65536
#define SIG_OFF_F 5.0f
#define DMIN_F 2.0f

#define NBX 64
#define NBY 64
#define NBINS (NBX * NBY)

__device__ __forceinline__ float sigmoidf(float x) {
    return 1.0f / (1.0f + expf(-x));
}

// ---------- Pass 1: bin rays by panorama position (direction-derived) ----------
__global__ __launch_bounds__(256) void bin_count(
    const float* __restrict__ directions,
    int* __restrict__ keys,
    int* __restrict__ hist)
{
    const int r = blockIdx.x * 256 + threadIdx.x;   // grid sized exactly NRAYS
    const float dx = directions[r * 3 + 0];
    const float dy = directions[r * 3 + 1];
    const float dz = directions[r * 3 + 2];
    const float gx = dz;                                     // ~ per-layer gx
    const float gy = atan2f(dy, -dx) * 0.31830988618379067f; // ~ per-layer gy
    int kx = (int)((gx + 1.0f) * 0.5f * (float)NBX);
    int ky = (int)((gy + 1.0f) * 0.5f * (float)NBY);
    kx = min(max(kx, 0), NBX - 1);
    ky = min(max(ky, 0), NBY - 1);
    const int key = ky * NBX + kx;
    keys[r] = key;
    atomicAdd(&hist[key], 1);
}

// ---------- Pass 2: exclusive scan of the 4096-bin histogram (1 block) ----------
__global__ __launch_bounds__(1024) void scan_bins(
    const int* __restrict__ hist,
    int* __restrict__ offs)
{
    __shared__ int s_wave[16];
    __shared__ int s_waveoff[16];
    const int t = threadIdx.x;
    const int4 v = ((const int4*)hist)[t];          // 4 bins per thread
    const int total = v.x + v.y + v.z + v.w;
    const int lane = t & 63, wid = t >> 6;
    int inc = total;
    #pragma unroll
    for (int off = 1; off < 64; off <<= 1) {
        const int u = __shfl_up(inc, off, 64);
        if (lane >= off) inc += u;
    }
    if (lane == 63) s_wave[wid] = inc;
    __syncthreads();
    if (t == 0) {
        int acc = 0;
        for (int i = 0; i < 16; ++i) { s_waveoff[i] = acc; acc += s_wave[i]; }
    }
    __syncthreads();
    const int excl = s_waveoff[wid] + inc - total;  // exclusive prefix of this chunk
    offs[4 * t + 0] = excl;
    offs[4 * t + 1] = excl + v.x;
    offs[4 * t + 2] = excl + v.x + v.y;
    offs[4 * t + 3] = excl + v.x + v.y + v.z;
}

// ---------- Pass 3: scatter ray ids into bin-sorted permutation ----------
__global__ __launch_bounds__(256) void scatter_rays(
    const int* __restrict__ keys,
    int* __restrict__ offs,     // consumed as cursors
    int* __restrict__ perm)
{
    const int r = blockIdx.x * 256 + threadIdx.x;
    const int key = keys[r];
    const int pos = atomicAdd(&offs[key], 1);
    perm[pos] = r;
}

// ---------- Pass 4: render. One thread per (ray, layer); 32 lanes = one ray ----------
__global__ __launch_bounds__(256) void msi_forward(
    const float* __restrict__ origins,
    const float* __restrict__ directions,
    const float* __restrict__ alpha,
    const float* __restrict__ rgb,
    const float* __restrict__ layer_deltas,
    const float* __restrict__ center,
    const int* __restrict__ perm,
    float* __restrict__ out)
{
    __shared__ float s_radii[LTOT];
    if (threadIdx.x == 0) {
        float r = DMIN_F;                  // radii = cumsum([DMIN] ++ exp(deltas))
        s_radii[0] = r;
        for (int i = 0; i < LTOT - 1; ++i) {
            r += expf(layer_deltas[i]);
            s_radii[i + 1] = r;
        }
    }
    __syncthreads();

    const int gid  = blockIdx.x * 256 + threadIdx.x;
    const int ray  = perm[gid >> 5];       // bin-sorted processing order
    const int lane = threadIdx.x & 31;     // layer index

    const float cx = center[0], cy = center[1], cz = center[2];
    const float ox = origins[ray * 3 + 0];
    const float oy = origins[ray * 3 + 1];
    const float oz = origins[ray * 3 + 2];
    const float dxv = directions[ray * 3 + 0];
    const float dyv = directions[ray * 3 + 1];
    const float dzv = directions[ray * 3 + 2];

    const float rx = ox - cx, ry = oy - cy, rz = oz - cz;
    const float a  = dxv * dxv + dyv * dyv + dzv * dzv;
    const float b  = 2.0f * (dxv * rx + dyv * ry + dzv * rz);
    const float c0 = rx * rx + ry * ry + rz * rz;

    const float r    = s_radii[lane];
    const float c    = c0 - r * r;
    const float disc = b * b - 4.0f * a * c;
    const float sq   = sqrtf(fmaxf(disc, 0.0f));
    const float t0   = (-b + sq) / (2.0f * a);
    const float t1   = (-b - sq) / (2.0f * a);
    const bool  mask = (t0 * t1) < 0.0f;

    const float px = (ox + dxv * t0) - cx;
    const float py = (oy + dyv * t0) - cy;
    const float pz = (oz + dzv * t0) - cz;
    const float nx = px / r, ny = py / r, nz = pz / r;

    const float gx = nz;
    const float gy = atan2f(ny, -nx) * 0.31830988618379067f;

    const float x   = (gx + 1.0f) * 0.5f * (float)(WW - 1);
    const float y   = (gy + 1.0f) * 0.5f * (float)(HH - 1);
    const float x0f = floorf(x), y0f = floorf(y);
    const float wx  = x - x0f,  wy  = y - y0f;
    int ix0 = (int)x0f, iy0 = (int)y0f;
    int ix1 = ix0 + 1,  iy1 = iy0 + 1;
    ix0 = min(max(ix0, 0), WW - 1);
    ix1 = min(max(ix1, 0), WW - 1);
    iy0 = min(max(iy0, 0), HH - 1);
    iy1 = min(max(iy1, 0), HH - 1);

    const float w00 = (1.0f - wx) * (1.0f - wy);
    const float w01 = wx * (1.0f - wy);
    const float w10 = (1.0f - wx) * wy;
    const float w11 = wx * wy;

    const int i00 = iy0 * WW + ix0;
    const int i01 = iy0 * WW + ix1;
    const int i10 = iy1 * WW + ix0;
    const int i11 = iy1 * WW + ix1;

    const float* ap = alpha + (size_t)lane * HWSZ;
    const float sv = ap[i00] * w00 + ap[i01] * w01 + ap[i10] * w10 + ap[i11] * w11;
    float av = sigmoidf(sv - SIG_OFF_F);
    av = mask ? av : 0.0f;

    // RGB at even-layer coords (gx[::NSUB] + repeat); even lanes fetch, shared via shfl
    float cr = 0.0f, cg = 0.0f, cb = 0.0f;
    if ((lane & 1) == 0) {
        const float* rp = rgb + (size_t)(lane >> 1) * 3 * HWSZ;
        {
            const float* q = rp;
            cr = sigmoidf(q[i00] * w00 + q[i01] * w01 + q[i10] * w10 + q[i11] * w11);
        }
        {
            const float* q = rp + HWSZ;
            cg = sigmoidf(q[i00] * w00 + q[i01] * w01 + q[i10] * w10 + q[i11] * w11);
        }
        {
            const float* q = rp + 2 * HWSZ;
            cb = sigmoidf(q[i00] * w00 + q[i01] * w01 + q[i10] * w10 + q[i11] * w11);
        }
    }
    const int src = lane & ~1;
    cr = __shfl(cr, src, 32);
    cg = __shfl(cg, src, 32);
    cb = __shfl(cb, src, 32);

    // Exclusive prefix product of (1 - alpha) over the 32-lane group
    float p = 1.0f - av;
    #pragma unroll
    for (int off = 1; off < 32; off <<= 1) {
        const float v = __shfl_up(p, off, 32);
        if (lane >= off) p *= v;
    }
    float trans = __shfl_up(p, 1, 32);
    if (lane == 0) trans = 1.0f;
    const float wgt = av * trans;

    float accR = wgt * cr;
    float accG = wgt * cg;
    float accB = wgt * cb;
    #pragma unroll
    for (int off = 16; off >= 1; off >>= 1) {
        accR += __shfl_xor(accR, off, 32);
        accG += __shfl_xor(accG, off, 32);
        accB += __shfl_xor(accB, off, 32);
    }
    if (lane == 0) {
        out[ray * 3 + 0] = accR;
        out[ray * 3 + 1] = accG;
        out[ray * 3 + 2] = accB;
    }
}

extern "C" void kernel_launch(void* const* d_in, const int* in_sizes, int n_in,
                              void* d_out, int out_size, void* d_ws, size_t ws_size,
                              hipStream_t stream) {
    const float* origins      = (const float*)d_in[0];
    const float* directions   = (const float*)d_in[1];
    const float* alpha        = (const float*)d_in[2];
    const float* rgb          = (const float*)d_in[3];
    const float* layer_deltas = (const float*)d_in[4];
    const float* center       = (const float*)d_in[5];
    float* out = (float*)d_out;

    // workspace layout (all 256B-aligned): hist | offs | keys | perm
    char* ws  = (char*)d_ws;
    int* hist = (int*)(ws);
    int* offs = (int*)(ws + 16384);
    int* keys = (int*)(ws + 32768);
    int* perm = (int*)(ws + 32768 + NRAYS * sizeof(int));

    hipMemsetAsync(hist, 0, NBINS * sizeof(int), stream);
    bin_count<<<NRAYS / 256, 256, 0, stream>>>(directions, keys, hist);
    scan_bins<<<1, 1024, 0, stream>>>(hist, offs);
    scatter_rays<<<NRAYS / 256, 256, 0, stream>>>(keys, offs, perm);

    const int blocks = (NRAYS * LTOT) / 256;   // 8192
    msi_forward<<<blocks, 256, 0, stream>>>(origins, directions, alpha, rgb,
                                            layer_deltas, center, perm, out);
}